// Round 6
// baseline (111.405 us; speedup 1.0000x reference)
//
#include <hip/hip_runtime.h>

// rfft512 over 32768 rows, one wave64 per TWO rows (sequential in-wave,
// loads for both rows issued up front for 2x memory-level parallelism).
// z[n] = x[2n] + i*x[2n+1] -> FFT_256 (Stockham radix-4 DIF, 4 stages) ->
// rfft untangle -> bins 0..256 (Re plane then Im plane).
//
// Stage A is fused with the global load (lane t's read set {z[t], z[t+64],
// z[t+128], z[t+192]} is coalesced dwordx2). Stages B..D via XOR-swizzled
// float2 LDS ping-pong. Final outputs are staged through LDS and stored as
// dwordx4 (rows are 1028 B = 4B-aligned only; f4u tolerates align 4).
// Wave-synchronous: one wave owns its rows; stage boundaries need only
// s_waitcnt lgkmcnt(0) (wave64 lockstep; DS ops of a wave retire in order).

#define NFFT 512
#define WPB  4   // waves per 256-thread block; each wave does 2 rows

typedef float f4u __attribute__((ext_vector_type(4), aligned(4)));

__device__ __forceinline__ int SW(int i) { return i ^ ((i >> 2) & 12); }

__device__ __forceinline__ void waveSyncLds() {
    asm volatile("s_waitcnt lgkmcnt(0)" ::: "memory");
}

__global__ __launch_bounds__(256) void rfft512_kernel(
    const float* __restrict__ x, float* __restrict__ out, int batch)
{
    __shared__ __align__(16) float2 lds[WPB][2][256];
    const int t = threadIdx.x & 63;
    const int w = threadIdx.x >> 6;
    const long long b0 = ((long long)blockIdx.x * WPB + w) * 2;  // rows b0, b0+1

    float2* buf0 = lds[w][0];
    float2* buf1 = lds[w][1];
    const float NEG2PI = -6.28318530717958647692f;
    const float C45 = 0.70710678118654752440f;

    // ---- Issue ALL global loads for both rows up front (8 dwordx2, 4 KB/wave in flight).
    float2 L[2][4];
#pragma unroll
    for (int r = 0; r < 2; ++r) {
        const float2* xf2 = (const float2*)(x + (b0 + r) * NFFT);
        L[r][0] = xf2[t];
        L[r][1] = xf2[t + 64];
        L[r][2] = xf2[t + 128];
        L[r][3] = xf2[t + 192];
    }

    // ---- Untangle twiddles (row-independent): w(t+64j) = w(t)*exp(-i*pi*j/4).
    float wr[4], wi[4];
    {
        float sn, cs;
        __sincosf(NEG2PI * (float)t * (1.0f / 512.0f), &sn, &cs);
        wr[0] = cs;              wi[0] = sn;
        wr[1] = C45 * (cs + sn); wi[1] = C45 * (sn - cs);
        wr[2] = sn;              wi[2] = -cs;
        wr[3] = C45 * (sn - cs); wi[3] = -C45 * (cs + sn);
    }

#pragma unroll
    for (int r = 0; r < 2; ++r) {
        const long long b = b0 + r;

        // ---- Stage A (n=256, s=1, p=t), in-register from staged loads.
        {
            float2 a = L[r][0], bb = L[r][1], c = L[r][2], d = L[r][3];
            float apcr = a.x + c.x, apci = a.y + c.y;
            float amcr = a.x - c.x, amci = a.y - c.y;
            float bpdr = bb.x + d.x, bpdi = bb.y + d.y;
            float bmdr = bb.x - d.x, bmdi = bb.y - d.y;
            float y0r = apcr + bpdr, y0i = apci + bpdi;
            float u1r = amcr + bmdi, u1i = amci - bmdr;
            float u2r = apcr - bpdr, u2i = apci - bpdi;
            float u3r = amcr - bmdi, u3i = amci + bmdr;
            float sn, cs;
            __sincosf(NEG2PI * (float)t * (1.0f / 256.0f), &sn, &cs);
            float w1r = cs, w1i = sn;
            float w2r = cs * cs - sn * sn, w2i = 2.0f * cs * sn;
            float w3r = w1r * w2r - w1i * w2i, w3i = w1r * w2i + w1i * w2r;
            int wb = (4 * t) ^ (t & 12);           // SW(4t), multiple of 4
            float4* d4 = (float4*)buf1;
            d4[wb >> 1]       = make_float4(y0r, y0i,
                                            w1r * u1r - w1i * u1i, w1r * u1i + w1i * u1r);
            d4[(wb >> 1) + 1] = make_float4(w2r * u2r - w2i * u2i, w2r * u2i + w2i * u2r,
                                            w3r * u3r - w3i * u3i, w3r * u3i + w3i * u3r);
        }
        waveSyncLds();

        // ---- Stage B: n=64, s=4 : p=t>>2, wbase=(t&3)+16*(t>>2), ws=4
        {
            int rb = SW(t);
            float2 a = buf1[rb], bb = buf1[rb + 64], c = buf1[rb + 128], d = buf1[rb + 192];
            float apcr = a.x + c.x, apci = a.y + c.y;
            float amcr = a.x - c.x, amci = a.y - c.y;
            float bpdr = bb.x + d.x, bpdi = bb.y + d.y;
            float bmdr = bb.x - d.x, bmdi = bb.y - d.y;
            float y0r = apcr + bpdr, y0i = apci + bpdi;
            float u1r = amcr + bmdi, u1i = amci - bmdr;
            float u2r = apcr - bpdr, u2i = apci - bpdi;
            float u3r = amcr - bmdi, u3i = amci + bmdr;
            float sn, cs;
            __sincosf(NEG2PI * (float)(t >> 2) * (1.0f / 64.0f), &sn, &cs);
            float w1r = cs, w1i = sn;
            float w2r = cs * cs - sn * sn, w2i = 2.0f * cs * sn;
            float w3r = w1r * w2r - w1i * w2i, w3i = w1r * w2i + w1i * w2r;
            int wbase = (t & 3) + 16 * (t >> 2);
            buf0[SW(wbase)]      = make_float2(y0r, y0i);
            buf0[SW(wbase + 4)]  = make_float2(w1r * u1r - w1i * u1i, w1r * u1i + w1i * u1r);
            buf0[SW(wbase + 8)]  = make_float2(w2r * u2r - w2i * u2i, w2r * u2i + w2i * u2r);
            buf0[SW(wbase + 12)] = make_float2(w3r * u3r - w3i * u3i, w3r * u3i + w3i * u3r);
        }
        waveSyncLds();

        // ---- Stage C: n=16, s=16 : p=t>>4, wbase=(t&15)+64*(t>>4), ws=16
        {
            int rb = SW(t);
            float2 a = buf0[rb], bb = buf0[rb + 64], c = buf0[rb + 128], d = buf0[rb + 192];
            float apcr = a.x + c.x, apci = a.y + c.y;
            float amcr = a.x - c.x, amci = a.y - c.y;
            float bpdr = bb.x + d.x, bpdi = bb.y + d.y;
            float bmdr = bb.x - d.x, bmdi = bb.y - d.y;
            float y0r = apcr + bpdr, y0i = apci + bpdi;
            float u1r = amcr + bmdi, u1i = amci - bmdr;
            float u2r = apcr - bpdr, u2i = apci - bpdi;
            float u3r = amcr - bmdi, u3i = amci + bmdr;
            float sn, cs;
            __sincosf(NEG2PI * (float)(t >> 4) * (1.0f / 16.0f), &sn, &cs);
            float w1r = cs, w1i = sn;
            float w2r = cs * cs - sn * sn, w2i = 2.0f * cs * sn;
            float w3r = w1r * w2r - w1i * w2i, w3i = w1r * w2i + w1i * w2r;
            int wbase = (t & 15) + 64 * (t >> 4);
            buf1[SW(wbase)]      = make_float2(y0r, y0i);
            buf1[SW(wbase + 16)] = make_float2(w1r * u1r - w1i * u1i, w1r * u1i + w1i * u1r);
            buf1[SW(wbase + 32)] = make_float2(w2r * u2r - w2i * u2i, w2r * u2i + w2i * u2r);
            buf1[SW(wbase + 48)] = make_float2(w3r * u3r - w3i * u3i, w3r * u3i + w3i * u3r);
        }
        waveSyncLds();

        // ---- Stage D: n=4, s=64 : p=0, lane-local. Keep Z[t+64j] in regs;
        // write to buf0 for the untangle partner gather.
        float zr[4], zi[4];
        {
            int rb = SW(t);
            float2 a = buf1[rb], bb = buf1[rb + 64], c = buf1[rb + 128], d = buf1[rb + 192];
            float apcr = a.x + c.x, apci = a.y + c.y;
            float amcr = a.x - c.x, amci = a.y - c.y;
            float bpdr = bb.x + d.x, bpdi = bb.y + d.y;
            float bmdr = bb.x - d.x, bmdi = bb.y - d.y;
            zr[0] = apcr + bpdr; zi[0] = apci + bpdi;
            zr[1] = amcr + bmdi; zi[1] = amci - bmdr;
            zr[2] = apcr - bpdr; zi[2] = apci - bpdi;
            zr[3] = amcr - bmdi; zi[3] = amci + bmdr;
            buf0[rb]       = make_float2(zr[0], zi[0]);
            buf0[rb + 64]  = make_float2(zr[1], zi[1]);
            buf0[rb + 128] = make_float2(zr[2], zi[2]);
            buf0[rb + 192] = make_float2(zr[3], zi[3]);
        }
        waveSyncLds();

        // ---- Untangle (k=t+64j) -> stage into buf1 as flat floats.
        // buf1 (512 floats) = Re[0..255] | Im[0..255]; bin 256 handled by lane 0.
        float* fre = (float*)buf1;
        float* fim = fre + 256;
#pragma unroll
        for (int j = 0; j < 4; ++j) {
            int k = t + 64 * j;
            int km = (256 - k) & 255;
            float2 pm = buf0[SW(km)];
            float S = zr[j] + pm.x;        // 2*Ar
            float T = zi[j] - pm.y;        // 2*Ai
            float U = zi[j] + pm.y;        // 2*Br
            float V = zr[j] - pm.x;        // -2*Bi
            fre[k] = 0.5f * (S + wr[j] * U + wi[j] * V);
            fim[k] = 0.5f * (T - wr[j] * V + wi[j] * U);
        }
        waveSyncLds();

        // ---- Wide stores: lane t stores Re[4t..4t+3] and Im[4t..4t+3].
        float* outRe = out + b * 257;
        float* outIm = out + (long long)batch * 257 + b * 257;
        float4 vRe = ((const float4*)fre)[t];
        float4 vIm = ((const float4*)fim)[t];
        *(f4u*)(outRe + 4 * t) = (f4u){vRe.x, vRe.y, vRe.z, vRe.w};
        *(f4u*)(outIm + 4 * t) = (f4u){vIm.x, vIm.y, vIm.z, vIm.w};
        if (t == 0) {
            outRe[256] = zr[0] - zi[0];    // X[256] = Re(Z[0]) - Im(Z[0])
            outIm[256] = 0.0f;
        }
        waveSyncLds();   // protect buf1 (staging) from next row's stage-A writes
    }
}

extern "C" void kernel_launch(void* const* d_in, const int* in_sizes, int n_in,
                              void* d_out, int out_size, void* d_ws, size_t ws_size,
                              hipStream_t stream)
{
    const float* x = (const float*)d_in[0];
    float* out = (float*)d_out;
    const int batch = in_sizes[0] / NFFT;              // 32768
    const int grid = (batch + WPB * 2 - 1) / (WPB * 2);  // 4096 blocks of 256
    rfft512_kernel<<<grid, 256, 0, stream>>>(x, out, batch);
}